// Round 1
// baseline (615.967 us; speedup 1.0000x reference)
//
#include <hip/hip_runtime.h>
#include <hip/hip_bf16.h>

// LSTM cell, fused: gates = [x|h] @ [Wx;Wh] + b ; elementwise -> (h_new, c_new)
// N = 262144 rows, F=64, H=128, K=192, 512 gate columns.
// v2: LDS-free streaming. Each wave loads its A-fragments (8 contiguous floats)
// directly from global (L1/L2-hot, shared across the block's 4 waves), converts
// to bf16 in-register, prefetches c_t before the MFMA loop, no barriers.
// Weights pre-swizzled to b-frag layout in d_ws (L2-resident).

#define N_ROWS (64 * 4096)
#define HDIM 128
#define FDIM 64
#define KDIM 192
#define NKS 12          // k-steps of 16
#define M_TILE 32       // rows per block

typedef __bf16 bf16_t;
typedef __bf16 bf16x8 __attribute__((ext_vector_type(8)));
typedef float f32x16 __attribute__((ext_vector_type(16)));

// ---------------- prologue: swizzle weights fp32 -> bf16 b-frag layout ----------
// Bsw halfword index = ((ks*16 + ct)*64 + lane)*8 + j
//   holds B[k = ks*16 + (lane>>5)*8 + j][n = ct*32 + (lane&31)]
// where B = [Wx;Wh] concat over k (192) and gates concat over n (512).
__global__ void swizzle_weights(const float* __restrict__ Wxi, const float* __restrict__ Whi,
                                const float* __restrict__ Wxf, const float* __restrict__ Whf,
                                const float* __restrict__ Wxc, const float* __restrict__ Whc,
                                const float* __restrict__ Wxo, const float* __restrict__ Who,
                                bf16_t* __restrict__ Bsw) {
    int gid = blockIdx.x * 256 + threadIdx.x;      // 0 .. 12287
    int l  = gid & 63;
    int ct = (gid >> 6) & 15;
    int ks = gid >> 10;
    int kb = ks * 16 + (l >> 5) * 8;               // 8 consecutive k, never straddles 64
    int n  = ct * 32 + (l & 31);
    int g  = n >> 7;
    int c  = n & 127;
    const float* Wx = (g == 0) ? Wxi : (g == 1) ? Wxf : (g == 2) ? Wxc : Wxo;
    const float* Wh = (g == 0) ? Whi : (g == 1) ? Whf : (g == 2) ? Whc : Who;
    bf16x8 v;
#pragma unroll
    for (int j = 0; j < 8; ++j) {
        int k = kb + j;
        float f = (k < FDIM) ? Wx[k * HDIM + c] : Wh[(k - FDIM) * HDIM + c];
        v[j] = (bf16_t)f;
    }
    *(bf16x8*)(Bsw + (long)gid * 8) = v;
}

// ---------------- helpers ----------------
__device__ inline float fast_rcp(float x) { return __builtin_amdgcn_rcpf(x); }
__device__ inline float sigm(float x) {
    x = fminf(fmaxf(x, -30.f), 30.f);
    return fast_rcp(1.f + __expf(-x));
}
__device__ inline float tanh_f(float x) {
    x = fminf(fmaxf(x, -15.f), 15.f);
    float e = __expf(-2.f * x);
    return (1.f - e) * fast_rcp(1.f + e);
}

// ---------------- main fused kernel ----------------
__global__ __launch_bounds__(256, 3)
void lstm_fused(const float* __restrict__ x, const float* __restrict__ h_t,
                const float* __restrict__ c_t,
                const float* __restrict__ b_i, const float* __restrict__ b_f,
                const float* __restrict__ b_c, const float* __restrict__ b_o,
                const bf16_t* __restrict__ Bsw,
                float* __restrict__ h_out, float* __restrict__ c_out) {
    const int tid  = threadIdx.x;
    const int wave = tid >> 6;     // 0..3 -> col slice wave*32 of H
    const int lane = tid & 63;
    const long row_base = (long)blockIdx.x * M_TILE;

    // A-fragment source: row = lane&31, k-slice = (lane>>5)*8 (+ j in 0..7)
    const int arow = lane & 31;
    const int ksl  = (lane >> 5) * 8;
    const float* ax = x   + (row_base + arow) * FDIM + ksl;   // 32B aligned
    const float* ah = h_t + (row_base + arow) * HDIM + ksl;   // 32B aligned

    // epilogue coordinates (C/D layout: col = lane&31, row = (r&3)+8*(r>>2)+4*(lane>>5))
    const int col   = wave * 32 + (lane & 31);
    const int rhalf = 4 * (lane >> 5);

    // prefetch c_t (16 dwords) + biases -> their HBM latency hides under the MFMAs
    float cpre[16];
#pragma unroll
    for (int r = 0; r < 16; ++r) {
        int row_l = (r & 3) + 8 * (r >> 2) + rhalf;
        cpre[r] = c_t[(row_base + row_l) * HDIM + col];
    }
    const float bi = b_i[col], bf = b_f[col], bc = b_c[col], bo = b_o[col];

    f32x16 acc0 = {}, acc1 = {}, acc2 = {}, acc3 = {};   // gates i,f,c,o
    const bf16_t* b_base = Bsw + wave * 512 + (long)lane * 8;

#pragma unroll
    for (int ks = 0; ks < NKS; ++ks) {
        // A: 8 consecutive fp32 from x (ks<4) or h (ks>=4), convert to bf16
        const float* ap = (ks < 4) ? (ax + ks * 16) : (ah + (ks - 4) * 16);
        float4 f0 = *(const float4*)(ap);
        float4 f1 = *(const float4*)(ap + 4);
        bf16x8 a;
        a[0] = (bf16_t)f0.x; a[1] = (bf16_t)f0.y; a[2] = (bf16_t)f0.z; a[3] = (bf16_t)f0.w;
        a[4] = (bf16_t)f1.x; a[5] = (bf16_t)f1.y; a[6] = (bf16_t)f1.z; a[7] = (bf16_t)f1.w;

        const bf16_t* bp = b_base + (long)ks * 8192;
        bf16x8 b0 = *(const bf16x8*)(bp);                        // gate i tile
        bf16x8 b1 = *(const bf16x8*)(bp + 2048);                 // gate f
        bf16x8 b2 = *(const bf16x8*)(bp + 4096);                 // gate c
        bf16x8 b3 = *(const bf16x8*)(bp + 6144);                 // gate o
        acc0 = __builtin_amdgcn_mfma_f32_32x32x16_bf16(a, b0, acc0, 0, 0, 0);
        acc1 = __builtin_amdgcn_mfma_f32_32x32x16_bf16(a, b1, acc1, 0, 0, 0);
        acc2 = __builtin_amdgcn_mfma_f32_32x32x16_bf16(a, b2, acc2, 0, 0, 0);
        acc3 = __builtin_amdgcn_mfma_f32_32x32x16_bf16(a, b3, acc3, 0, 0, 0);
    }

    // epilogue: fused gate math, c_t already in registers
#pragma unroll
    for (int r = 0; r < 16; ++r) {
        int row_l = (r & 3) + 8 * (r >> 2) + rhalf;
        long idx = (row_base + row_l) * HDIM + col;
        float gi = acc0[r] + bi;
        float gf = acc1[r] + bf;
        float gc = acc2[r] + bc;
        float go = acc3[r] + bo;
        float i_t = sigm(gi);
        float f_t = sigm(gf);
        float ch  = tanh_f(gc);
        float o_t = sigm(go);
        float cn = f_t * cpre[r] + i_t * ch;
        float hn = o_t * tanh_f(cn);
        h_out[idx] = hn;
        c_out[idx] = cn;
    }
}

extern "C" void kernel_launch(void* const* d_in, const int* in_sizes, int n_in,
                              void* d_out, int out_size, void* d_ws, size_t ws_size,
                              hipStream_t stream) {
    const float* x    = (const float*)d_in[0];
    const float* h_t  = (const float*)d_in[1];
    const float* c_t  = (const float*)d_in[2];
    const float* W_xi = (const float*)d_in[3];
    const float* W_hi = (const float*)d_in[4];
    const float* b_i  = (const float*)d_in[5];
    const float* W_xf = (const float*)d_in[6];
    const float* W_hf = (const float*)d_in[7];
    const float* b_f  = (const float*)d_in[8];
    const float* W_xc = (const float*)d_in[9];
    const float* W_hc = (const float*)d_in[10];
    const float* b_c  = (const float*)d_in[11];
    const float* W_xo = (const float*)d_in[12];
    const float* W_ho = (const float*)d_in[13];
    const float* b_o  = (const float*)d_in[14];

    bf16_t* Bsw = (bf16_t*)d_ws;                  // 196608 bytes
    float* h_out = (float*)d_out;
    float* c_out = h_out + (long)N_ROWS * HDIM;

    swizzle_weights<<<48, 256, 0, stream>>>(W_xi, W_hi, W_xf, W_hf,
                                            W_xc, W_hc, W_xo, W_ho, Bsw);
    lstm_fused<<<N_ROWS / M_TILE, 256, 0, stream>>>(x, h_t, c_t, b_i, b_f, b_c, b_o,
                                                    Bsw, h_out, c_out);
}